// Round 10
// baseline (1031.016 us; speedup 1.0000x reference)
//
#include <hip/hip_runtime.h>

#define BATCH 32
#define ATOMS 128
#define CCH 3
#define XH 57
#define XW 57
#define OHH 64
#define OWW 64
#define KSEL 2000
#define PIX (XH*XW)            // 3249
#define NPS (ATOMS*PIX)        // 415872 per-sample X elements
#define NTOT (BATCH*NPS)       // 13307904
#define RPS (CCH*OHH*OWW)      // 12288 per-sample R elements
#define RTOT (BATCH*RPS)       // 393216
#define CANDCAP 32768
#define NW 24576               // weight elements 128*3*8*8
#define WSEG 102               // write_k segments of 1024 float4 per sample

// ---------------------------------------------------------------------------
// Prep (once): weight f64 layouts + Rd = -Y init.
// ---------------------------------------------------------------------------
__global__ __launch_bounds__(256) void prep_k(const float* __restrict__ Wg,
    double* __restrict__ WDd, double* __restrict__ Wt2d,
    const float* __restrict__ Y, double* __restrict__ Rd) {
  int e = blockIdx.x * 256 + threadIdx.x;
  if (e < NW) {
    {
      int kw = e & 7; int t = e >> 3; int c = t % 3; t /= 3; int kh = t & 7; int a = t >> 3;
      WDd[e] = (double)Wg[(a*3 + c)*64 + kh*8 + kw];
    }
    {
      int a = e & 127; int t = e >> 7; int j = t & 7; int i = (t >> 3) & 7; int c = t >> 6;
      Wt2d[e] = (double)Wg[(a*3 + c)*64 + j*8 + i];
    }
  }
  if (e < RTOT) Rd[e] = -(double)Y[e];
}

// ---------------------------------------------------------------------------
// DENSE R += D(X) (iteration 0 only). Verified round-8 version, unchanged.
// ---------------------------------------------------------------------------
__global__ __launch_bounds__(256) void convD_k(const float* __restrict__ X,
    const double* __restrict__ WDd, double* __restrict__ Rd) {
  __shared__ float Xs[8][11][72];             // 25344 B
  int p = blockIdx.x;
  int lg = (p & 7) * 256 + (p >> 3);          // bijective: 2048 = 8*256
  int b = lg >> 6; int rem = lg & 63;
  int band = rem >> 2, quarter = rem & 3;
  int row0 = band * 4;
  int a_base = quarter * 32;
  int tid = threadIdx.x;
  int ox = tid & 63;
  int wv = __builtin_amdgcn_readfirstlane(tid >> 6);
  const float* Xb = X + (size_t)b * NPS;

  double acc[4][3];
#pragma unroll
  for (int ty = 0; ty < 4; ++ty)
#pragma unroll
    for (int c = 0; c < 3; ++c) acc[ty][c] = 0.0;

  for (int ch = 0; ch < 4; ++ch) {
    __syncthreads();
    for (int e = tid; e < 8 * 11 * 72; e += 256) {
      int ai = e / 792; int rem2 = e - ai * 792;
      int r = rem2 / 72; int ss = rem2 - r * 72;
      int gy = row0 - 7 + r;
      int xcol = ss - 7;
      int a = a_base + ch * 8 + ai;
      float v = 0.0f;
      if ((unsigned)xcol < (unsigned)XW && (unsigned)gy < (unsigned)XH)
        v = Xb[a * PIX + gy * XW + xcol];
      Xs[ai][r][ss] = v;
    }
    __syncthreads();
#pragma unroll
    for (int jj = 0; jj < 2; ++jj) {
      int ai = (wv << 1) + jj;
      int a  = a_base + ch * 8 + ai;
      const double* Wa = WDd + a * 192;       // [kh][c][kw]
#pragma unroll
      for (int r = 0; r < 11; ++r) {
        int gy = row0 - 7 + r;
        if ((unsigned)gy >= (unsigned)XH) continue;   // uniform
        double xd[8];
#pragma unroll
        for (int t = 0; t < 8; ++t) xd[t] = (double)Xs[ai][r][ox + t];
#pragma unroll
        for (int ty = 0; ty < 4; ++ty) {
          int kh = ty + 7 - r;
          if ((unsigned)kh < 8u) {
            const double* Wk = Wa + kh * 24;
#pragma unroll
            for (int kw = 0; kw < 8; ++kw) {
              acc[ty][0] = fma(xd[7 - kw], Wk[kw],      acc[ty][0]);
              acc[ty][1] = fma(xd[7 - kw], Wk[8 + kw],  acc[ty][1]);
              acc[ty][2] = fma(xd[7 - kw], Wk[16 + kw], acc[ty][2]);
            }
          }
        }
      }
    }
  }
#pragma unroll
  for (int ty = 0; ty < 4; ++ty) {
    int oy = row0 + ty;
#pragma unroll
    for (int c = 0; c < 3; ++c)
      atomicAdd(&Rd[((size_t)(b * CCH + c) << 12) + (oy << 6) + ox], acc[ty][c]);
  }
}

// ---------------------------------------------------------------------------
// SPARSE R = D(X) - Y (iterations 1,2). Verified, unchanged.
// ---------------------------------------------------------------------------
__global__ __launch_bounds__(256) void convD_sparse_k(const float* __restrict__ Wg,
    const int* __restrict__ nzidx, const float* __restrict__ nzval,
    const float* __restrict__ Y, float* __restrict__ R) {
  __shared__ double accd[512];       // [rr][ox]
  __shared__ float Wf[8192];         // [a][kh][kw] for this c
  __shared__ int   li[KSEL];
  __shared__ float lv[KSEL];
  int p = blockIdx.x;
  int lg = (p & 7) * 96 + (p >> 3);  // bijective: 768 = 8*96
  int s = lg / 24; int r = lg % 24; int c = r >> 3; int band = r & 7;
  int row0 = band * 8;
  int tid = threadIdx.x;
  for (int e = tid; e < 512; e += 256) accd[e] = 0.0;
  for (int e = tid; e < 8192; e += 256) {
    int a = e >> 6, k2 = e & 63;
    Wf[e] = Wg[(a * 3 + c) * 64 + k2];
  }
  for (int e = tid; e < KSEL; e += 256) {
    li[e] = nzidx[s * KSEL + e];
    lv[e] = nzval[s * KSEL + e];
  }
  __syncthreads();
  int slot = tid >> 3, kw = tid & 7;
  for (int e = slot; e < KSEL; e += 32) {
    int idx = li[e];
    int a = (int)((unsigned)idx / 3249u);
    int pp = idx - a * 3249;
    int y = (int)((unsigned)pp / 57u);
    int x = pp - y * 57;
    int dy = y - row0;
    if (dy < -7 || dy > 7) continue;
    double val = (double)lv[e];
    const float* wp = Wf + (a << 6) + kw;
#pragma unroll
    for (int kh = 0; kh < 8; ++kh) {
      int rr = dy + kh;
      if ((unsigned)rr < 8u)
        __hip_atomic_fetch_add(&accd[(rr << 6) + x + kw],
                               val * (double)wp[kh << 3],
                               __ATOMIC_RELAXED, __HIP_MEMORY_SCOPE_WORKGROUP);
    }
  }
  __syncthreads();
  const float* Yb = Y + (((size_t)(s * CCH + c)) << 12) + (row0 << 6);
  float* Rb = R + (((size_t)(s * CCH + c)) << 12) + (row0 << 6);
  for (int e = tid; e < 512; e += 256)
    Rb[e] = (float)(accd[e] - (double)Yb[e]);
}

// ---------------------------------------------------------------------------
// HT = Xprev - Dt(R), f64 VALU (verified round-8 core), fused level-1 hist.
// SPX=true (it>=1): Xprev reconstructed in LDS from the nz list (exactly the
// thresholded values, bit-identical) -> no 53MB Xprev stream, and write_k
// needn't store intermediate X at all.
// ---------------------------------------------------------------------------
template <typename TR, bool SPX>
__global__ __launch_bounds__(256) void convDt_k(const TR* __restrict__ R,
    const double* __restrict__ Wt2d, const float* __restrict__ Xprev,
    const int* __restrict__ nzidx, const float* __restrict__ nzval,
    float* __restrict__ HT, unsigned* __restrict__ g1) {
  __shared__ float Rl[3][15][72];
  __shared__ unsigned hh[1024];      // packed: 2 u16 bins per word
  __shared__ float Xp[8][8][XW];     // 14592 B (SPX only)
  int p = blockIdx.x;
  int lg = (p & 7) * 512 + (p >> 3);  // bijective: 4096 = 8*512
  int b = lg >> 7; int rem = lg & 127; int ag = rem >> 3; int by = rem & 7;
  int row0 = by * 8;
  int a0 = ag * 8;
  int tid = threadIdx.x;
  for (int e = tid; e < 1024; e += 256) hh[e] = 0;
  for (int e = tid; e < 3 * 15 * 72; e += 256) {
    int c = e / (15 * 72); int r2 = e - c * (15 * 72);
    int rr = r2 / 72; int cc = r2 - rr * 72;
    int gr = row0 + rr;
    float v = 0.0f;
    if (cc < OWW && gr < OHH)
      v = (float)R[((size_t)(b * CCH + c) << 12) + (gr << 6) + cc];
    Rl[c][rr][cc] = v;
  }
  if constexpr (SPX) {
    for (int e = tid; e < 8 * 8 * XW; e += 256) (&Xp[0][0][0])[e] = 0.0f;
    __syncthreads();
    for (int e = tid; e < KSEL; e += 256) {
      int idx = nzidx[b * KSEL + e];
      int a = (int)((unsigned)idx / 3249u);
      int pp2 = idx - a * 3249;
      int yy = (int)((unsigned)pp2 / 57u);
      int xx = pp2 - yy * 57;
      if ((unsigned)(a - a0) < 8u && (unsigned)(yy - row0) < 8u)
        Xp[a - a0][yy - row0][xx] = nzval[b * KSEL + e];
    }
  }
  __syncthreads();
  int x = tid & 63, yg = tid >> 6;
  int yb = yg * 2;
  double acc[8][2];
#pragma unroll
  for (int aa = 0; aa < 8; ++aa) { acc[aa][0] = 0.0; acc[aa][1] = 0.0; }

#pragma unroll 1
  for (int c = 0; c < 3; ++c) {
#pragma unroll 1
    for (int j = 0; j < 8; ++j) {
      double rw[9];
#pragma unroll
      for (int r = 0; r < 9; ++r) rw[r] = (double)Rl[c][yb + r][x + j];
#pragma unroll
      for (int i = 0; i < 8; ++i) {
        const double* wp = Wt2d + ((c * 8 + i) * 8 + j) * 128 + a0;  // uniform
#pragma unroll
        for (int aa = 0; aa < 8; ++aa) {
          double w = wp[aa];
          acc[aa][0] = fma(rw[i + 0], w, acc[aa][0]);
          acc[aa][1] = fma(rw[i + 1], w, acc[aa][1]);
        }
      }
    }
  }
  if (x < XW) {
#pragma unroll
    for (int ty = 0; ty < 2; ++ty) {
      int yy = row0 + yb + ty;
      if (yy < XH) {
#pragma unroll
        for (int aa = 0; aa < 8; ++aa) {
          size_t xo = (size_t)(b * ATOMS + a0 + aa) * PIX + yy * XW + x;
          double xprev;
          if constexpr (SPX) xprev = (double)Xp[aa][yb + ty][x];
          else               xprev = (double)Xprev[xo];
          float fv = (float)(xprev - acc[aa][ty]);
          HT[xo] = fv;
          unsigned u = __float_as_uint(fv) & 0x7fffffffu;
          unsigned bin = u >> 20;
          atomicAdd(&hh[bin >> 1], 1u << ((bin & 1) << 4));
        }
      }
    }
  }
  __syncthreads();
  unsigned* gp = g1 + (size_t)b * 2048;
  for (int e = tid; e < 1024; e += 256) {
    unsigned v = hh[e];
    unsigned lo = v & 0xffffu, hi = v >> 16;
    if (lo) atomicAdd(&gp[2 * e], lo);
    if (hi) atomicAdd(&gp[2 * e + 1], hi);
  }
}

// ---------------------------------------------------------------------------
// Level 2: float4 scan with FUSED level-1 rank find (recomputed from g1 per
// block, deterministic); per-block LDS candidate aggregation.
// ---------------------------------------------------------------------------
__global__ __launch_bounds__(256) void hist2_k(const float* __restrict__ HT,
    const unsigned* __restrict__ g1, unsigned* __restrict__ g2,
    int* __restrict__ cand, int* __restrict__ candcnt) {
  __shared__ unsigned h[1024];
  __shared__ unsigned part[256];
  __shared__ int lidx[4096];
  __shared__ int lcnt, lbase, b1_sh;
  int tid = threadIdx.x;
  int s = blockIdx.x >> 5;
  int chunk = blockIdx.x & 31;
  const unsigned* hg1 = g1 + (size_t)s * 2048;
  // fused find1: bin of rank KSEL over 2048 bins (descending)
  unsigned psum = 0;
#pragma unroll
  for (int e = 0; e < 8; ++e) psum += hg1[tid * 8 + e];
  part[tid] = psum;
  for (int e = tid; e < 1024; e += 256) h[e] = 0;
  if (tid == 0) lcnt = 0;
  __syncthreads();
  if (tid == 0) {
    int Kv = KSEL;
    unsigned cumBefore = 0;
    int bsel = 0;
    for (int q = 255; q >= 0; --q) {
      unsigned ps = part[q];
      if ((int)(cumBefore + ps) >= Kv) {
        for (int e = q * 8 + 7;; --e) {
          unsigned c2 = cumBefore + hg1[e];
          if ((int)c2 >= Kv) { bsel = e; break; }
          cumBefore = c2;
        }
        break;
      }
      cumBefore += ps;
    }
    b1_sh = bsel;
  }
  __syncthreads();
  unsigned pre = (unsigned)b1_sh;
  const uint4* U4 = (const uint4*)(HT + (size_t)s * NPS);
  for (int i4 = chunk * 256 + tid; i4 < NPS / 4; i4 += 32 * 256) {
    uint4 v = U4[i4];
    unsigned uu[4] = {v.x, v.y, v.z, v.w};
#pragma unroll
    for (int t = 0; t < 4; ++t) {
      unsigned u = uu[t] & 0x7fffffffu;
      if ((u >> 20) == pre) {
        atomicAdd(&h[(u >> 10) & 1023], 1u);
        int pos = atomicAdd(&lcnt, 1);           // LDS atomic, cheap
        if (pos < 4096) lidx[pos] = i4 * 4 + t;
      }
    }
  }
  __syncthreads();
  if (tid == 0) {
    int n = lcnt < 4096 ? lcnt : 4096;
    lbase = atomicAdd(&candcnt[s], n);           // ONE global atomic/block
  }
  __syncthreads();
  int n = lcnt < 4096 ? lcnt : 4096;
  int base = lbase;
  for (int e = tid; e < n; e += 256) {
    int g = base + e;
    if (g < CANDCAP) cand[s * CANDCAP + g] = lidx[e];
  }
  for (int e = tid; e < 1024; e += 256)
    if (h[e]) atomicAdd(&g2[s * 1024 + e], h[e]);
}

// ---------------------------------------------------------------------------
// Fused find1 + find2 + level 3 + tie resolution (one block per sample).
// ---------------------------------------------------------------------------
__global__ __launch_bounds__(256) void pass3_k(const float* __restrict__ HT,
    const int* __restrict__ cand, const int* __restrict__ candcnt,
    const unsigned* __restrict__ g1, const unsigned* __restrict__ g2,
    unsigned* __restrict__ tau_out, int* __restrict__ cutoff_out) {
  int s = blockIdx.x;
  __shared__ unsigned h[1024];
  __shared__ unsigned part[256];
  __shared__ int eqidx[1024];
  __shared__ int eqn;
  __shared__ unsigned tau_sh;
  __shared__ int k3_sh;
  __shared__ int b1_sh, k1_sh, b2_sh, k2_sh;
  int t = threadIdx.x;
  // ---- find1 over g1[2048] ----
  const unsigned* hg1 = g1 + (size_t)s * 2048;
  unsigned s1 = 0;
#pragma unroll
  for (int e = 0; e < 8; ++e) s1 += hg1[t * 8 + e];
  part[t] = s1;
  for (int e = t; e < 1024; e += 256) h[e] = 0;
  if (t == 0) eqn = 0;
  __syncthreads();
  if (t == 0) {
    int Kv = KSEL;
    unsigned cumBefore = 0;
    int bsel = 0;
    for (int q = 255; q >= 0; --q) {
      unsigned ps = part[q];
      if ((int)(cumBefore + ps) >= Kv) {
        for (int e = q * 8 + 7;; --e) {
          unsigned c2 = cumBefore + hg1[e];
          if ((int)c2 >= Kv) { bsel = e; break; }
          cumBefore = c2;
        }
        break;
      }
      cumBefore += ps;
    }
    b1_sh = bsel;
    k1_sh = Kv - (int)cumBefore;
  }
  __syncthreads();
  // ---- find2 over g2[1024] ----
  const unsigned* hg = g2 + s * 1024;
  unsigned s2 = 0;
#pragma unroll
  for (int e = 0; e < 4; ++e) s2 += hg[t * 4 + e];
  part[t] = s2;
  __syncthreads();
  if (t == 0) {
    int Kv = k1_sh;
    unsigned cumBefore = 0;
    int bsel = 0;
    for (int q = 255; q >= 0; --q) {
      unsigned ps = part[q];
      if ((int)(cumBefore + ps) >= Kv) {
        for (int e = q * 4 + 3;; --e) {
          unsigned c2 = cumBefore + hg[e];
          if ((int)c2 >= Kv) { bsel = e; break; }
          cumBefore = c2;
        }
        break;
      }
      cumBefore += ps;
    }
    b2_sh = bsel;
    k2_sh = Kv - (int)cumBefore;
  }
  __syncthreads();
  // ---- level 3 over candidates ----
  int n = candcnt[s];
  if (n > CANDCAP) n = CANDCAP;
  unsigned pre21 = (((unsigned)b1_sh) << 10) | (unsigned)b2_sh;
  const unsigned* U = (const unsigned*)(HT + (size_t)s * NPS);
  for (int e = t; e < n; e += 256) {
    int i = cand[s * CANDCAP + e];
    unsigned u = U[i] & 0x7fffffffu;
    if ((u >> 10) == pre21) atomicAdd(&h[u & 1023], 1u);
  }
  __syncthreads();
  if (t == 0) {
    int Kv = k2_sh;
    unsigned cumBefore = 0;
    int b3 = 0;
    for (int e = 1023; e >= 0; --e) {
      unsigned c2 = cumBefore + h[e];
      if ((int)c2 >= Kv) { b3 = e; break; }
      cumBefore = c2;
    }
    tau_sh = (pre21 << 10) | (unsigned)b3;
    k3_sh = Kv - (int)cumBefore;
  }
  __syncthreads();
  unsigned tau = tau_sh;
  for (int e = t; e < n; e += 256) {
    int i = cand[s * CANDCAP + e];
    unsigned u = U[i] & 0x7fffffffu;
    if (u == tau) {
      int pos = atomicAdd(&eqn, 1);
      if (pos < 1024) eqidx[pos] = i;
    }
  }
  __syncthreads();
  if (t == 0) {
    int m = eqn < 1024 ? eqn : 1024;
    int k3 = k3_sh;
    int cutoff;
    if (k3 >= m) {
      cutoff = 0x7fffffff;
    } else {
      int last = -1;
      for (int r = 0; r < k3; ++r) {
        int mn = 0x7fffffff;
        for (int q = 0; q < m; ++q) {
          int v = eqidx[q];
          if (v > last && v < mn) mn = v;
        }
        last = mn;
      }
      cutoff = last;
    }
    tau_out[s] = tau;
    cutoff_out[s] = cutoff;
  }
}

// ---------------------------------------------------------------------------
// Threshold scan: emits nz list (it<2) and/or stores Xout (it==2 only —
// intermediate X lives solely as the nz list now).
// ---------------------------------------------------------------------------
__global__ __launch_bounds__(256) void write_k(const float* __restrict__ HT,
    const unsigned* __restrict__ tau, const int* __restrict__ cutoff,
    float* __restrict__ Xo, int* __restrict__ nzidx, float* __restrict__ nzval,
    int* __restrict__ nzcnt, int store_x) {
  __shared__ int lidx[2048];
  __shared__ float lval[2048];
  __shared__ int lcnt, lbase;
  int s = blockIdx.x / WSEG;
  int seg = blockIdx.x % WSEG;
  int tid = threadIdx.x;
  bool emit = (nzidx != nullptr);
  if (tid == 0) lcnt = 0;
  __syncthreads();
  unsigned tt = tau[s];
  int co = cutoff[s];
  size_t sbase = (size_t)s * NPS;
  const float4* H4 = (const float4*)(HT + sbase);
  float4* X4 = (float4*)(Xo + sbase);
  int f0 = seg * 1024;
#pragma unroll
  for (int rr = 0; rr < 4; ++rr) {
    int i4 = f0 + rr * 256 + tid;
    if (i4 < NPS / 4) {
      float4 v = H4[i4];
      float vv[4] = {v.x, v.y, v.z, v.w};
      float oo[4];
#pragma unroll
      for (int t = 0; t < 4; ++t) {
        int il = i4 * 4 + t;
        unsigned u = __float_as_uint(vv[t]) & 0x7fffffffu;
        bool keep = (u > tt) || (u == tt && il <= co);
        oo[t] = keep ? vv[t] : 0.0f;
        if (keep && emit) {
          int pos = atomicAdd(&lcnt, 1);
          if (pos < 2048) { lidx[pos] = il; lval[pos] = vv[t]; }
        }
      }
      if (store_x) X4[i4] = make_float4(oo[0], oo[1], oo[2], oo[3]);
    }
  }
  if (!emit) return;
  __syncthreads();
  if (tid == 0) lbase = atomicAdd(&nzcnt[s], lcnt);
  __syncthreads();
  int n = lcnt < 2048 ? lcnt : 2048;
  int base = lbase;
  for (int e = tid; e < n; e += 256) {
    int g = base + e;
    if (g < KSEL) { nzidx[s * KSEL + g] = lidx[e]; nzval[s * KSEL + g] = lval[e]; }
  }
}

extern "C" void kernel_launch(void* const* d_in, const int* in_sizes, int n_in,
                              void* d_out, int out_size, void* d_ws, size_t ws_size,
                              hipStream_t stream) {
  const float* Y  = (const float*)d_in[0];
  const float* X0 = (const float*)d_in[1];
  const float* Wg = (const float*)d_in[2];
  float* Xout = (float*)d_out;

  double* WDd  = (double*)d_ws;                        // NW f64
  double* Wt2d = WDd + NW;                             // NW f64
  float* HT   = (float*)(Wt2d + NW);                   // NTOT f32
  float* Rbuf = HT + NTOT;                             // RTOT f32
  double* Rd  = (double*)(Rbuf + RTOT);                // RTOT f64
  unsigned* g1 = (unsigned*)(Rd + RTOT);               // 32*2048
  unsigned* g2 = g1 + 32 * 2048;                       // 32*1024
  int* candcnt = (int*)(g2 + 32 * 1024);               // 32
  int* nzcnt = candcnt + 32;                           // 32
  unsigned* tau = (unsigned*)(nzcnt + 32);
  int* cutoff = (int*)(tau + 32);
  int* cand = cutoff + 32;                             // 32*CANDCAP
  int* nzidx = cand + 32 * CANDCAP;                    // 32*KSEL
  float* nzval = (float*)(nzidx + 32 * KSEL);          // 32*KSEL
  size_t zero_bytes = (size_t)(32 * 2048 + 32 * 1024 + 32 + 32) * 4;

  prep_k<<<dim3((RTOT + 255) / 256), dim3(256), 0, stream>>>(Wg, WDd, Wt2d, Y, Rd);

  for (int it = 0; it < 3; ++it) {
    hipMemsetAsync(g1, 0, zero_bytes, stream);  // g1, g2, candcnt, nzcnt
    if (it == 0) {
      convD_k<<<dim3(2048), dim3(256), 0, stream>>>(X0, WDd, Rd);
      convDt_k<double, false><<<dim3(4096), dim3(256), 0, stream>>>(
          Rd, Wt2d, X0, nullptr, nullptr, HT, g1);
    } else {
      convD_sparse_k<<<dim3(BATCH * CCH * 8), dim3(256), 0, stream>>>(
          Wg, nzidx, nzval, Y, Rbuf);
      convDt_k<float, true><<<dim3(4096), dim3(256), 0, stream>>>(
          Rbuf, Wt2d, nullptr, nzidx, nzval, HT, g1);
    }
    hist2_k<<<dim3(BATCH * 32), dim3(256), 0, stream>>>(HT, g1, g2, cand, candcnt);
    pass3_k<<<dim3(BATCH), dim3(256), 0, stream>>>(HT, cand, candcnt, g1, g2, tau, cutoff);
    bool last = (it == 2);
    write_k<<<dim3(BATCH * WSEG), dim3(256), 0, stream>>>(HT, tau, cutoff, Xout,
        last ? nullptr : nzidx, last ? nullptr : nzval, nzcnt, last ? 1 : 0);
  }
}

// Round 11
// 1019.511 us; speedup vs baseline: 1.0113x; 1.0113x over previous
//
#include <hip/hip_runtime.h>

#define BATCH 32
#define ATOMS 128
#define CCH 3
#define XH 57
#define XW 57
#define OHH 64
#define OWW 64
#define KSEL 2000
#define PIX (XH*XW)            // 3249
#define NPS (ATOMS*PIX)        // 415872 per-sample X elements
#define NTOT (BATCH*NPS)       // 13307904
#define RPS (CCH*OHH*OWW)      // 12288 per-sample R elements
#define RTOT (BATCH*RPS)       // 393216
#define CANDCAP 32768
#define NW 24576               // weight elements 128*3*8*8
#define WSEG 102               // write_k segments of 1024 float4 per sample
#define ZWORDS (32*2048 + 32*1024)   // g1+g2 words zeroed between iterations

// ---------------------------------------------------------------------------
// Prep (once): weight f64 layouts, Rd = -Y init, zero g1/g2/candcnt/nzcnt.
// ---------------------------------------------------------------------------
__global__ __launch_bounds__(256) void prep_k(const float* __restrict__ Wg,
    double* __restrict__ WDd, double* __restrict__ Wt2d,
    const float* __restrict__ Y, double* __restrict__ Rd,
    unsigned* __restrict__ zbuf) {
  int e = blockIdx.x * 256 + threadIdx.x;
  if (e < NW) {
    {
      int kw = e & 7; int t = e >> 3; int c = t % 3; t /= 3; int kh = t & 7; int a = t >> 3;
      WDd[e] = (double)Wg[(a*3 + c)*64 + kh*8 + kw];
    }
    {
      int a = e & 127; int t = e >> 7; int j = t & 7; int i = (t >> 3) & 7; int c = t >> 6;
      Wt2d[e] = (double)Wg[(a*3 + c)*64 + j*8 + i];
    }
  }
  if (e < RTOT) Rd[e] = -(double)Y[e];
  if (e < ZWORDS + 64) zbuf[e] = 0;   // g1, g2, candcnt, nzcnt (contiguous)
}

// ---------------------------------------------------------------------------
// DENSE R += D(X) (iteration 0 only). Block = (b, 4-row band, atom-quarter).
// X converted to f64 ONCE at staging (Xs f64 [4][11][72] = 25.3KB, same LDS
// as before) -> per-use cvt count 640 -> ~99 per thread. 8 chunks x 4 atoms;
// wave handles 1 atom/chunk. acc[4][3] f64. 4 contributors per Rd address.
// ---------------------------------------------------------------------------
__global__ __launch_bounds__(256) void convD_k(const float* __restrict__ X,
    const double* __restrict__ WDd, double* __restrict__ Rd) {
  __shared__ double Xs[4][11][72];            // 25344 B
  int p = blockIdx.x;
  int lg = (p & 7) * 256 + (p >> 3);          // bijective: 2048 = 8*256
  int b = lg >> 6; int rem = lg & 63;
  int band = rem >> 2, quarter = rem & 3;
  int row0 = band * 4;
  int a_base = quarter * 32;
  int tid = threadIdx.x;
  int ox = tid & 63;
  int wv = __builtin_amdgcn_readfirstlane(tid >> 6);
  const float* Xb = X + (size_t)b * NPS;

  double acc[4][3];
#pragma unroll
  for (int ty = 0; ty < 4; ++ty)
#pragma unroll
    for (int c = 0; c < 3; ++c) acc[ty][c] = 0.0;

  for (int ch = 0; ch < 8; ++ch) {
    __syncthreads();
    for (int e = tid; e < 4 * 11 * 72; e += 256) {
      int ai = e / 792; int rem2 = e - ai * 792;
      int r = rem2 / 72; int ss = rem2 - r * 72;
      int gy = row0 - 7 + r;
      int xcol = ss - 7;
      int a = a_base + ch * 4 + ai;
      float v = 0.0f;
      if ((unsigned)xcol < (unsigned)XW && (unsigned)gy < (unsigned)XH)
        v = Xb[a * PIX + gy * XW + xcol];
      Xs[ai][r][ss] = (double)v;
    }
    __syncthreads();
    {
      int a = a_base + ch * 4 + wv;
      const double* Wa = WDd + a * 192;       // [kh][c][kw]
#pragma unroll
      for (int r = 0; r < 11; ++r) {
        int gy = row0 - 7 + r;
        if ((unsigned)gy >= (unsigned)XH) continue;   // uniform
        double xd[8];
#pragma unroll
        for (int t = 0; t < 8; ++t) xd[t] = Xs[wv][r][ox + t];
#pragma unroll
        for (int ty = 0; ty < 4; ++ty) {
          int kh = ty + 7 - r;
          if ((unsigned)kh < 8u) {
            const double* Wk = Wa + kh * 24;
#pragma unroll
            for (int kw = 0; kw < 8; ++kw) {
              acc[ty][0] = fma(xd[7 - kw], Wk[kw],      acc[ty][0]);
              acc[ty][1] = fma(xd[7 - kw], Wk[8 + kw],  acc[ty][1]);
              acc[ty][2] = fma(xd[7 - kw], Wk[16 + kw], acc[ty][2]);
            }
          }
        }
      }
    }
  }
#pragma unroll
  for (int ty = 0; ty < 4; ++ty) {
    int oy = row0 + ty;
#pragma unroll
    for (int c = 0; c < 3; ++c)
      atomicAdd(&Rd[((size_t)(b * CCH + c) << 12) + (oy << 6) + ox], acc[ty][c]);
  }
}

// ---------------------------------------------------------------------------
// SPARSE R = D(X) - Y (iterations 1,2). Verified, unchanged.
// ---------------------------------------------------------------------------
__global__ __launch_bounds__(256) void convD_sparse_k(const float* __restrict__ Wg,
    const int* __restrict__ nzidx, const float* __restrict__ nzval,
    const float* __restrict__ Y, float* __restrict__ R) {
  __shared__ double accd[512];       // [rr][ox]
  __shared__ float Wf[8192];         // [a][kh][kw] for this c
  __shared__ int   li[KSEL];
  __shared__ float lv[KSEL];
  int p = blockIdx.x;
  int lg = (p & 7) * 96 + (p >> 3);  // bijective: 768 = 8*96
  int s = lg / 24; int r = lg % 24; int c = r >> 3; int band = r & 7;
  int row0 = band * 8;
  int tid = threadIdx.x;
  for (int e = tid; e < 512; e += 256) accd[e] = 0.0;
  for (int e = tid; e < 8192; e += 256) {
    int a = e >> 6, k2 = e & 63;
    Wf[e] = Wg[(a * 3 + c) * 64 + k2];
  }
  for (int e = tid; e < KSEL; e += 256) {
    li[e] = nzidx[s * KSEL + e];
    lv[e] = nzval[s * KSEL + e];
  }
  __syncthreads();
  int slot = tid >> 3, kw = tid & 7;
  for (int e = slot; e < KSEL; e += 32) {
    int idx = li[e];
    int a = (int)((unsigned)idx / 3249u);
    int pp = idx - a * 3249;
    int y = (int)((unsigned)pp / 57u);
    int x = pp - y * 57;
    int dy = y - row0;
    if (dy < -7 || dy > 7) continue;
    double val = (double)lv[e];
    const float* wp = Wf + (a << 6) + kw;
#pragma unroll
    for (int kh = 0; kh < 8; ++kh) {
      int rr = dy + kh;
      if ((unsigned)rr < 8u)
        __hip_atomic_fetch_add(&accd[(rr << 6) + x + kw],
                               val * (double)wp[kh << 3],
                               __ATOMIC_RELAXED, __HIP_MEMORY_SCOPE_WORKGROUP);
    }
  }
  __syncthreads();
  const float* Yb = Y + (((size_t)(s * CCH + c)) << 12) + (row0 << 6);
  float* Rb = R + (((size_t)(s * CCH + c)) << 12) + (row0 << 6);
  for (int e = tid; e < 512; e += 256)
    Rb[e] = (float)(accd[e] - (double)Yb[e]);
}

// ---------------------------------------------------------------------------
// HT = Xprev - Dt(R), f64 VALU, fused level-1 hist. r8-verified version
// (non-SPX: dense Xprev stream, 17KB LDS -> 8 blocks/CU).
// ---------------------------------------------------------------------------
template <typename TR>
__global__ __launch_bounds__(256) void convDt_k(const TR* __restrict__ R,
    const double* __restrict__ Wt2d, const float* __restrict__ Xprev,
    float* __restrict__ HT, unsigned* __restrict__ g1) {
  __shared__ float Rl[3][15][72];
  __shared__ unsigned hh[1024];      // packed: 2 u16 bins per word
  int p = blockIdx.x;
  int lg = (p & 7) * 512 + (p >> 3);  // bijective: 4096 = 8*512
  int b = lg >> 7; int rem = lg & 127; int ag = rem >> 3; int by = rem & 7;
  int row0 = by * 8;
  int a0 = ag * 8;
  int tid = threadIdx.x;
  for (int e = tid; e < 1024; e += 256) hh[e] = 0;
  for (int e = tid; e < 3 * 15 * 72; e += 256) {
    int c = e / (15 * 72); int r2 = e - c * (15 * 72);
    int rr = r2 / 72; int cc = r2 - rr * 72;
    int gr = row0 + rr;
    float v = 0.0f;
    if (cc < OWW && gr < OHH)
      v = (float)R[((size_t)(b * CCH + c) << 12) + (gr << 6) + cc];
    Rl[c][rr][cc] = v;
  }
  __syncthreads();
  int x = tid & 63, yg = tid >> 6;
  int yb = yg * 2;
  double acc[8][2];
#pragma unroll
  for (int aa = 0; aa < 8; ++aa) { acc[aa][0] = 0.0; acc[aa][1] = 0.0; }

#pragma unroll 1
  for (int c = 0; c < 3; ++c) {
#pragma unroll 1
    for (int j = 0; j < 8; ++j) {
      double rw[9];
#pragma unroll
      for (int r = 0; r < 9; ++r) rw[r] = (double)Rl[c][yb + r][x + j];
#pragma unroll
      for (int i = 0; i < 8; ++i) {
        const double* wp = Wt2d + ((c * 8 + i) * 8 + j) * 128 + a0;  // uniform
#pragma unroll
        for (int aa = 0; aa < 8; ++aa) {
          double w = wp[aa];
          acc[aa][0] = fma(rw[i + 0], w, acc[aa][0]);
          acc[aa][1] = fma(rw[i + 1], w, acc[aa][1]);
        }
      }
    }
  }
  if (x < XW) {
#pragma unroll
    for (int ty = 0; ty < 2; ++ty) {
      int yy = row0 + yb + ty;
      if (yy < XH) {
#pragma unroll
        for (int aa = 0; aa < 8; ++aa) {
          size_t xo = (size_t)(b * ATOMS + a0 + aa) * PIX + yy * XW + x;
          float fv = (float)((double)Xprev[xo] - acc[aa][ty]);
          HT[xo] = fv;
          unsigned u = __float_as_uint(fv) & 0x7fffffffu;
          unsigned bin = u >> 20;
          atomicAdd(&hh[bin >> 1], 1u << ((bin & 1) << 4));
        }
      }
    }
  }
  __syncthreads();
  unsigned* gp = g1 + (size_t)b * 2048;
  for (int e = tid; e < 1024; e += 256) {
    unsigned v = hh[e];
    unsigned lo = v & 0xffffu, hi = v >> 16;
    if (lo) atomicAdd(&gp[2 * e], lo);
    if (hi) atomicAdd(&gp[2 * e + 1], hi);
  }
}

// ---------------------------------------------------------------------------
// Level 2: float4 scan with FUSED level-1 rank find (per block, from g1);
// per-block LDS candidate aggregation (one global atomic per block).
// ---------------------------------------------------------------------------
__global__ __launch_bounds__(256) void hist2_k(const float* __restrict__ HT,
    const unsigned* __restrict__ g1, unsigned* __restrict__ g2,
    int* __restrict__ cand, int* __restrict__ candcnt) {
  __shared__ unsigned h[1024];
  __shared__ unsigned part[256];
  __shared__ int lidx[4096];
  __shared__ int lcnt, lbase, b1_sh;
  int tid = threadIdx.x;
  int s = blockIdx.x >> 5;
  int chunk = blockIdx.x & 31;
  const unsigned* hg1 = g1 + (size_t)s * 2048;
  unsigned psum = 0;
#pragma unroll
  for (int e = 0; e < 8; ++e) psum += hg1[tid * 8 + e];
  part[tid] = psum;
  for (int e = tid; e < 1024; e += 256) h[e] = 0;
  if (tid == 0) lcnt = 0;
  __syncthreads();
  if (tid == 0) {
    int Kv = KSEL;
    unsigned cumBefore = 0;
    int bsel = 0;
    for (int q = 255; q >= 0; --q) {
      unsigned ps = part[q];
      if ((int)(cumBefore + ps) >= Kv) {
        for (int e = q * 8 + 7;; --e) {
          unsigned c2 = cumBefore + hg1[e];
          if ((int)c2 >= Kv) { bsel = e; break; }
          cumBefore = c2;
        }
        break;
      }
      cumBefore += ps;
    }
    b1_sh = bsel;
  }
  __syncthreads();
  unsigned pre = (unsigned)b1_sh;
  const uint4* U4 = (const uint4*)(HT + (size_t)s * NPS);
  for (int i4 = chunk * 256 + tid; i4 < NPS / 4; i4 += 32 * 256) {
    uint4 v = U4[i4];
    unsigned uu[4] = {v.x, v.y, v.z, v.w};
#pragma unroll
    for (int t = 0; t < 4; ++t) {
      unsigned u = uu[t] & 0x7fffffffu;
      if ((u >> 20) == pre) {
        atomicAdd(&h[(u >> 10) & 1023], 1u);
        int pos = atomicAdd(&lcnt, 1);           // LDS atomic, cheap
        if (pos < 4096) lidx[pos] = i4 * 4 + t;
      }
    }
  }
  __syncthreads();
  if (tid == 0) {
    int n = lcnt < 4096 ? lcnt : 4096;
    lbase = atomicAdd(&candcnt[s], n);           // ONE global atomic/block
  }
  __syncthreads();
  int n = lcnt < 4096 ? lcnt : 4096;
  int base = lbase;
  for (int e = tid; e < n; e += 256) {
    int g = base + e;
    if (g < CANDCAP) cand[s * CANDCAP + g] = lidx[e];
  }
  for (int e = tid; e < 1024; e += 256)
    if (h[e]) atomicAdd(&g2[s * 1024 + e], h[e]);
}

// ---------------------------------------------------------------------------
// Fused find1 + find2 + level 3 + tie resolution (one block per sample).
// Also zeroes candcnt/nzcnt for the next stage/iteration (after last use).
// ---------------------------------------------------------------------------
__global__ __launch_bounds__(256) void pass3_k(const float* __restrict__ HT,
    const int* __restrict__ cand, int* __restrict__ candcnt,
    const unsigned* __restrict__ g1, const unsigned* __restrict__ g2,
    int* __restrict__ nzcnt, unsigned* __restrict__ tau_out,
    int* __restrict__ cutoff_out) {
  int s = blockIdx.x;
  __shared__ unsigned h[1024];
  __shared__ unsigned part[256];
  __shared__ int eqidx[1024];
  __shared__ int eqn;
  __shared__ unsigned tau_sh;
  __shared__ int k3_sh;
  __shared__ int b1_sh, k1_sh, b2_sh, k2_sh;
  int t = threadIdx.x;
  const unsigned* hg1 = g1 + (size_t)s * 2048;
  unsigned s1 = 0;
#pragma unroll
  for (int e = 0; e < 8; ++e) s1 += hg1[t * 8 + e];
  part[t] = s1;
  for (int e = t; e < 1024; e += 256) h[e] = 0;
  if (t == 0) eqn = 0;
  __syncthreads();
  if (t == 0) {
    int Kv = KSEL;
    unsigned cumBefore = 0;
    int bsel = 0;
    for (int q = 255; q >= 0; --q) {
      unsigned ps = part[q];
      if ((int)(cumBefore + ps) >= Kv) {
        for (int e = q * 8 + 7;; --e) {
          unsigned c2 = cumBefore + hg1[e];
          if ((int)c2 >= Kv) { bsel = e; break; }
          cumBefore = c2;
        }
        break;
      }
      cumBefore += ps;
    }
    b1_sh = bsel;
    k1_sh = Kv - (int)cumBefore;
  }
  __syncthreads();
  const unsigned* hg = g2 + s * 1024;
  unsigned s2 = 0;
#pragma unroll
  for (int e = 0; e < 4; ++e) s2 += hg[t * 4 + e];
  part[t] = s2;
  __syncthreads();
  if (t == 0) {
    int Kv = k1_sh;
    unsigned cumBefore = 0;
    int bsel = 0;
    for (int q = 255; q >= 0; --q) {
      unsigned ps = part[q];
      if ((int)(cumBefore + ps) >= Kv) {
        for (int e = q * 4 + 3;; --e) {
          unsigned c2 = cumBefore + hg[e];
          if ((int)c2 >= Kv) { bsel = e; break; }
          cumBefore = c2;
        }
        break;
      }
      cumBefore += ps;
    }
    b2_sh = bsel;
    k2_sh = Kv - (int)cumBefore;
  }
  __syncthreads();
  int n = candcnt[s];
  if (n > CANDCAP) n = CANDCAP;
  unsigned pre21 = (((unsigned)b1_sh) << 10) | (unsigned)b2_sh;
  const unsigned* U = (const unsigned*)(HT + (size_t)s * NPS);
  for (int e = t; e < n; e += 256) {
    int i = cand[s * CANDCAP + e];
    unsigned u = U[i] & 0x7fffffffu;
    if ((u >> 10) == pre21) atomicAdd(&h[u & 1023], 1u);
  }
  __syncthreads();
  if (t == 0) {
    int Kv = k2_sh;
    unsigned cumBefore = 0;
    int b3 = 0;
    for (int e = 1023; e >= 0; --e) {
      unsigned c2 = cumBefore + h[e];
      if ((int)c2 >= Kv) { b3 = e; break; }
      cumBefore = c2;
    }
    tau_sh = (pre21 << 10) | (unsigned)b3;
    k3_sh = Kv - (int)cumBefore;
  }
  __syncthreads();
  unsigned tau = tau_sh;
  for (int e = t; e < n; e += 256) {
    int i = cand[s * CANDCAP + e];
    unsigned u = U[i] & 0x7fffffffu;
    if (u == tau) {
      int pos = atomicAdd(&eqn, 1);
      if (pos < 1024) eqidx[pos] = i;
    }
  }
  __syncthreads();
  if (t == 0) {
    int m = eqn < 1024 ? eqn : 1024;
    int k3 = k3_sh;
    int cutoff;
    if (k3 >= m) {
      cutoff = 0x7fffffff;
    } else {
      int last = -1;
      for (int r = 0; r < k3; ++r) {
        int mn = 0x7fffffff;
        for (int q = 0; q < m; ++q) {
          int v = eqidx[q];
          if (v > last && v < mn) mn = v;
        }
        last = mn;
      }
      cutoff = last;
    }
    tau_out[s] = tau;
    cutoff_out[s] = cutoff;
    candcnt[s] = 0;      // reset for next iteration (after last read)
    nzcnt[s] = 0;        // must be 0 before write_k accumulates
  }
}

// ---------------------------------------------------------------------------
// Threshold write (float4) + nz-list emit (non-last), per-block LDS
// aggregation. Also zeroes g1/g2 for the next iteration (zbuf != nullptr).
// ---------------------------------------------------------------------------
__global__ __launch_bounds__(256) void write_k(const float* __restrict__ HT,
    const unsigned* __restrict__ tau, const int* __restrict__ cutoff,
    float* __restrict__ Xo, int* __restrict__ nzidx, float* __restrict__ nzval,
    int* __restrict__ nzcnt, unsigned* __restrict__ zbuf) {
  __shared__ int lidx[2048];
  __shared__ float lval[2048];
  __shared__ int lcnt, lbase;
  int s = blockIdx.x / WSEG;
  int seg = blockIdx.x % WSEG;
  int tid = threadIdx.x;
  bool emit = (nzidx != nullptr);
  if (zbuf) {
    int e = blockIdx.x * 256 + tid;
    if (e < ZWORDS) zbuf[e] = 0;
  }
  if (tid == 0) lcnt = 0;
  __syncthreads();
  unsigned tt = tau[s];
  int co = cutoff[s];
  size_t sbase = (size_t)s * NPS;
  const float4* H4 = (const float4*)(HT + sbase);
  float4* X4 = (float4*)(Xo + sbase);
  int f0 = seg * 1024;
#pragma unroll
  for (int rr = 0; rr < 4; ++rr) {
    int i4 = f0 + rr * 256 + tid;
    if (i4 < NPS / 4) {
      float4 v = H4[i4];
      float vv[4] = {v.x, v.y, v.z, v.w};
      float oo[4];
#pragma unroll
      for (int t = 0; t < 4; ++t) {
        int il = i4 * 4 + t;
        unsigned u = __float_as_uint(vv[t]) & 0x7fffffffu;
        bool keep = (u > tt) || (u == tt && il <= co);
        oo[t] = keep ? vv[t] : 0.0f;
        if (keep && emit) {
          int pos = atomicAdd(&lcnt, 1);
          if (pos < 2048) { lidx[pos] = il; lval[pos] = vv[t]; }
        }
      }
      X4[i4] = make_float4(oo[0], oo[1], oo[2], oo[3]);
    }
  }
  if (!emit) return;
  __syncthreads();
  if (tid == 0) lbase = atomicAdd(&nzcnt[s], lcnt);
  __syncthreads();
  int n = lcnt < 2048 ? lcnt : 2048;
  int base = lbase;
  for (int e = tid; e < n; e += 256) {
    int g = base + e;
    if (g < KSEL) { nzidx[s * KSEL + g] = lidx[e]; nzval[s * KSEL + g] = lval[e]; }
  }
}

extern "C" void kernel_launch(void* const* d_in, const int* in_sizes, int n_in,
                              void* d_out, int out_size, void* d_ws, size_t ws_size,
                              hipStream_t stream) {
  const float* Y  = (const float*)d_in[0];
  const float* X0 = (const float*)d_in[1];
  const float* Wg = (const float*)d_in[2];
  float* Xout = (float*)d_out;

  double* WDd  = (double*)d_ws;                        // NW f64
  double* Wt2d = WDd + NW;                             // NW f64
  float* HT   = (float*)(Wt2d + NW);                   // NTOT f32
  float* Rbuf = HT + NTOT;                             // RTOT f32
  double* Rd  = (double*)(Rbuf + RTOT);                // RTOT f64
  unsigned* g1 = (unsigned*)(Rd + RTOT);               // 32*2048
  unsigned* g2 = g1 + 32 * 2048;                       // 32*1024
  int* candcnt = (int*)(g2 + 32 * 1024);               // 32
  int* nzcnt = candcnt + 32;                           // 32
  unsigned* tau = (unsigned*)(nzcnt + 32);
  int* cutoff = (int*)(tau + 32);
  int* cand = cutoff + 32;                             // 32*CANDCAP
  int* nzidx = cand + 32 * CANDCAP;                    // 32*KSEL
  float* nzval = (float*)(nzidx + 32 * KSEL);          // 32*KSEL

  prep_k<<<dim3((RTOT + 255) / 256), dim3(256), 0, stream>>>(Wg, WDd, Wt2d, Y, Rd, g1);

  for (int it = 0; it < 3; ++it) {
    const float* Xsrc = (it == 0) ? X0 : (const float*)Xout;
    if (it == 0) {
      convD_k<<<dim3(2048), dim3(256), 0, stream>>>(Xsrc, WDd, Rd);
      convDt_k<double><<<dim3(4096), dim3(256), 0, stream>>>(Rd, Wt2d, Xsrc, HT, g1);
    } else {
      convD_sparse_k<<<dim3(BATCH * CCH * 8), dim3(256), 0, stream>>>(
          Wg, nzidx, nzval, Y, Rbuf);
      convDt_k<float><<<dim3(4096), dim3(256), 0, stream>>>(Rbuf, Wt2d, Xsrc, HT, g1);
    }
    hist2_k<<<dim3(BATCH * 32), dim3(256), 0, stream>>>(HT, g1, g2, cand, candcnt);
    pass3_k<<<dim3(BATCH), dim3(256), 0, stream>>>(HT, cand, candcnt, g1, g2,
                                                   nzcnt, tau, cutoff);
    bool last = (it == 2);
    write_k<<<dim3(BATCH * WSEG), dim3(256), 0, stream>>>(HT, tau, cutoff, Xout,
        last ? nullptr : nzidx, last ? nullptr : nzval, nzcnt,
        last ? nullptr : g1);
  }
}

// Round 12
// 943.963 us; speedup vs baseline: 1.0922x; 1.0800x over previous
//
#include <hip/hip_runtime.h>

#define BATCH 32
#define ATOMS 128
#define CCH 3
#define XH 57
#define XW 57
#define OHH 64
#define OWW 64
#define KSEL 2000
#define PIX (XH*XW)            // 3249
#define NPS (ATOMS*PIX)        // 415872 per-sample X elements
#define NTOT (BATCH*NPS)       // 13307904
#define RPS (CCH*OHH*OWW)      // 12288 per-sample R elements
#define RTOT (BATCH*RPS)       // 393216
#define CANDCAP 32768
#define NW 24576               // weight elements 128*3*8*8
#define ZWORDS (32*2048 + 32*1024)   // g1+g2 words

// ---------------------------------------------------------------------------
// Prep (once): weight f64 layouts, Rd = -Y init, zero g1/g2/candcnt/nzcnt.
// ---------------------------------------------------------------------------
__global__ __launch_bounds__(256) void prep_k(const float* __restrict__ Wg,
    double* __restrict__ WDd, double* __restrict__ Wt2d,
    const float* __restrict__ Y, double* __restrict__ Rd,
    unsigned* __restrict__ zbuf) {
  int e = blockIdx.x * 256 + threadIdx.x;
  if (e < NW) {
    {
      int kw = e & 7; int t = e >> 3; int c = t % 3; t /= 3; int kh = t & 7; int a = t >> 3;
      WDd[e] = (double)Wg[(a*3 + c)*64 + kh*8 + kw];
    }
    {
      int a = e & 127; int t = e >> 7; int j = t & 7; int i = (t >> 3) & 7; int c = t >> 6;
      Wt2d[e] = (double)Wg[(a*3 + c)*64 + j*8 + i];
    }
  }
  if (e < RTOT) Rd[e] = -(double)Y[e];
  if (e < ZWORDS + 64) zbuf[e] = 0;   // g1, g2, candcnt, nzcnt (contiguous)
}

// ---------------------------------------------------------------------------
// DENSE R += D(X) (iteration 0 only). Verified r11 version, unchanged.
// ---------------------------------------------------------------------------
__global__ __launch_bounds__(256) void convD_k(const float* __restrict__ X,
    const double* __restrict__ WDd, double* __restrict__ Rd) {
  __shared__ double Xs[4][11][72];            // 25344 B
  int p = blockIdx.x;
  int lg = (p & 7) * 256 + (p >> 3);          // bijective: 2048 = 8*256
  int b = lg >> 6; int rem = lg & 63;
  int band = rem >> 2, quarter = rem & 3;
  int row0 = band * 4;
  int a_base = quarter * 32;
  int tid = threadIdx.x;
  int ox = tid & 63;
  int wv = __builtin_amdgcn_readfirstlane(tid >> 6);
  const float* Xb = X + (size_t)b * NPS;

  double acc[4][3];
#pragma unroll
  for (int ty = 0; ty < 4; ++ty)
#pragma unroll
    for (int c = 0; c < 3; ++c) acc[ty][c] = 0.0;

  for (int ch = 0; ch < 8; ++ch) {
    __syncthreads();
    for (int e = tid; e < 4 * 11 * 72; e += 256) {
      int ai = e / 792; int rem2 = e - ai * 792;
      int r = rem2 / 72; int ss = rem2 - r * 72;
      int gy = row0 - 7 + r;
      int xcol = ss - 7;
      int a = a_base + ch * 4 + ai;
      float v = 0.0f;
      if ((unsigned)xcol < (unsigned)XW && (unsigned)gy < (unsigned)XH)
        v = Xb[a * PIX + gy * XW + xcol];
      Xs[ai][r][ss] = (double)v;
    }
    __syncthreads();
    {
      int a = a_base + ch * 4 + wv;
      const double* Wa = WDd + a * 192;       // [kh][c][kw]
#pragma unroll
      for (int r = 0; r < 11; ++r) {
        int gy = row0 - 7 + r;
        if ((unsigned)gy >= (unsigned)XH) continue;   // uniform
        double xd[8];
#pragma unroll
        for (int t = 0; t < 8; ++t) xd[t] = Xs[wv][r][ox + t];
#pragma unroll
        for (int ty = 0; ty < 4; ++ty) {
          int kh = ty + 7 - r;
          if ((unsigned)kh < 8u) {
            const double* Wk = Wa + kh * 24;
#pragma unroll
            for (int kw = 0; kw < 8; ++kw) {
              acc[ty][0] = fma(xd[7 - kw], Wk[kw],      acc[ty][0]);
              acc[ty][1] = fma(xd[7 - kw], Wk[8 + kw],  acc[ty][1]);
              acc[ty][2] = fma(xd[7 - kw], Wk[16 + kw], acc[ty][2]);
            }
          }
        }
      }
    }
  }
#pragma unroll
  for (int ty = 0; ty < 4; ++ty) {
    int oy = row0 + ty;
#pragma unroll
    for (int c = 0; c < 3; ++c)
      atomicAdd(&Rd[((size_t)(b * CCH + c) << 12) + (oy << 6) + ox], acc[ty][c]);
  }
}

// ---------------------------------------------------------------------------
// SPARSE R = D(X) - Y (iterations 1,2). Verified, unchanged.
// ---------------------------------------------------------------------------
__global__ __launch_bounds__(256) void convD_sparse_k(const float* __restrict__ Wg,
    const int* __restrict__ nzidx, const float* __restrict__ nzval,
    const float* __restrict__ Y, float* __restrict__ R) {
  __shared__ double accd[512];       // [rr][ox]
  __shared__ float Wf[8192];         // [a][kh][kw] for this c
  __shared__ int   li[KSEL];
  __shared__ float lv[KSEL];
  int p = blockIdx.x;
  int lg = (p & 7) * 96 + (p >> 3);  // bijective: 768 = 8*96
  int s = lg / 24; int r = lg % 24; int c = r >> 3; int band = r & 7;
  int row0 = band * 8;
  int tid = threadIdx.x;
  for (int e = tid; e < 512; e += 256) accd[e] = 0.0;
  for (int e = tid; e < 8192; e += 256) {
    int a = e >> 6, k2 = e & 63;
    Wf[e] = Wg[(a * 3 + c) * 64 + k2];
  }
  for (int e = tid; e < KSEL; e += 256) {
    li[e] = nzidx[s * KSEL + e];
    lv[e] = nzval[s * KSEL + e];
  }
  __syncthreads();
  int slot = tid >> 3, kw = tid & 7;
  for (int e = slot; e < KSEL; e += 32) {
    int idx = li[e];
    int a = (int)((unsigned)idx / 3249u);
    int pp = idx - a * 3249;
    int y = (int)((unsigned)pp / 57u);
    int x = pp - y * 57;
    int dy = y - row0;
    if (dy < -7 || dy > 7) continue;
    double val = (double)lv[e];
    const float* wp = Wf + (a << 6) + kw;
#pragma unroll
    for (int kh = 0; kh < 8; ++kh) {
      int rr = dy + kh;
      if ((unsigned)rr < 8u)
        __hip_atomic_fetch_add(&accd[(rr << 6) + x + kw],
                               val * (double)wp[kh << 3],
                               __ATOMIC_RELAXED, __HIP_MEMORY_SCOPE_WORKGROUP);
    }
  }
  __syncthreads();
  const float* Yb = Y + (((size_t)(s * CCH + c)) << 12) + (row0 << 6);
  float* Rb = R + (((size_t)(s * CCH + c)) << 12) + (row0 << 6);
  for (int e = tid; e < 512; e += 256)
    Rb[e] = (float)(accd[e] - (double)Yb[e]);
}

// ---------------------------------------------------------------------------
// HT = Xprev - Dt(R), f64 VALU, fused level-1 hist. r8-verified, unchanged.
// ---------------------------------------------------------------------------
template <typename TR>
__global__ __launch_bounds__(256) void convDt_k(const TR* __restrict__ R,
    const double* __restrict__ Wt2d, const float* __restrict__ Xprev,
    float* __restrict__ HT, unsigned* __restrict__ g1) {
  __shared__ float Rl[3][15][72];
  __shared__ unsigned hh[1024];      // packed: 2 u16 bins per word
  int p = blockIdx.x;
  int lg = (p & 7) * 512 + (p >> 3);  // bijective: 4096 = 8*512
  int b = lg >> 7; int rem = lg & 127; int ag = rem >> 3; int by = rem & 7;
  int row0 = by * 8;
  int a0 = ag * 8;
  int tid = threadIdx.x;
  for (int e = tid; e < 1024; e += 256) hh[e] = 0;
  for (int e = tid; e < 3 * 15 * 72; e += 256) {
    int c = e / (15 * 72); int r2 = e - c * (15 * 72);
    int rr = r2 / 72; int cc = r2 - rr * 72;
    int gr = row0 + rr;
    float v = 0.0f;
    if (cc < OWW && gr < OHH)
      v = (float)R[((size_t)(b * CCH + c) << 12) + (gr << 6) + cc];
    Rl[c][rr][cc] = v;
  }
  __syncthreads();
  int x = tid & 63, yg = tid >> 6;
  int yb = yg * 2;
  double acc[8][2];
#pragma unroll
  for (int aa = 0; aa < 8; ++aa) { acc[aa][0] = 0.0; acc[aa][1] = 0.0; }

#pragma unroll 1
  for (int c = 0; c < 3; ++c) {
#pragma unroll 1
    for (int j = 0; j < 8; ++j) {
      double rw[9];
#pragma unroll
      for (int r = 0; r < 9; ++r) rw[r] = (double)Rl[c][yb + r][x + j];
#pragma unroll
      for (int i = 0; i < 8; ++i) {
        const double* wp = Wt2d + ((c * 8 + i) * 8 + j) * 128 + a0;  // uniform
#pragma unroll
        for (int aa = 0; aa < 8; ++aa) {
          double w = wp[aa];
          acc[aa][0] = fma(rw[i + 0], w, acc[aa][0]);
          acc[aa][1] = fma(rw[i + 1], w, acc[aa][1]);
        }
      }
    }
  }
  if (x < XW) {
#pragma unroll
    for (int ty = 0; ty < 2; ++ty) {
      int yy = row0 + yb + ty;
      if (yy < XH) {
#pragma unroll
        for (int aa = 0; aa < 8; ++aa) {
          size_t xo = (size_t)(b * ATOMS + a0 + aa) * PIX + yy * XW + x;
          float fv = (float)((double)Xprev[xo] - acc[aa][ty]);
          HT[xo] = fv;
          unsigned u = __float_as_uint(fv) & 0x7fffffffu;
          unsigned bin = u >> 20;
          atomicAdd(&hh[bin >> 1], 1u << ((bin & 1) << 4));
        }
      }
    }
  }
  __syncthreads();
  unsigned* gp = g1 + (size_t)b * 2048;
  for (int e = tid; e < 1024; e += 256) {
    unsigned v = hh[e];
    unsigned lo = v & 0xffffu, hi = v >> 16;
    if (lo) atomicAdd(&gp[2 * e], lo);
    if (hi) atomicAdd(&gp[2 * e + 1], hi);
  }
}

// ---------------------------------------------------------------------------
// histwrite_k: ONE scan of HT does everything element-wise:
//   bin > b1  -> certainly kept: Xout = val, emit to nz list (if emit)
//   bin < b1  -> certainly zero: Xout = 0
//   bin == b1 -> uncertain: Xout = val placeholder; gather candidate +
//                level-2 histogram (pass3 fixes these up)
// Replaces the old hist2 + write_k pair (kills one full 53MB pass + launch).
// b1 recomputed per block from g1 (deterministic). grid = 32*32.
// ---------------------------------------------------------------------------
__global__ __launch_bounds__(256) void histwrite_k(const float* __restrict__ HT,
    const unsigned* __restrict__ g1, unsigned* __restrict__ g2,
    int* __restrict__ cand, int* __restrict__ candcnt,
    float* __restrict__ Xo, int* __restrict__ nzidx, float* __restrict__ nzval,
    int* __restrict__ nzcnt, int emit) {
  __shared__ unsigned h[1024];
  __shared__ unsigned part[256];
  __shared__ int lidx[4096];
  __shared__ int kidx[2048];
  __shared__ float kval[2048];
  __shared__ int lcnt, lbase, kcnt, kbase, b1_sh;
  int tid = threadIdx.x;
  int s = blockIdx.x >> 5;
  int chunk = blockIdx.x & 31;
  const unsigned* hg1 = g1 + (size_t)s * 2048;
  unsigned psum = 0;
#pragma unroll
  for (int e = 0; e < 8; ++e) psum += hg1[tid * 8 + e];
  part[tid] = psum;
  for (int e = tid; e < 1024; e += 256) h[e] = 0;
  if (tid == 0) { lcnt = 0; kcnt = 0; }
  __syncthreads();
  if (tid == 0) {
    int Kv = KSEL;
    unsigned cumBefore = 0;
    int bsel = 0;
    for (int q = 255; q >= 0; --q) {
      unsigned ps = part[q];
      if ((int)(cumBefore + ps) >= Kv) {
        for (int e = q * 8 + 7;; --e) {
          unsigned c2 = cumBefore + hg1[e];
          if ((int)c2 >= Kv) { bsel = e; break; }
          cumBefore = c2;
        }
        break;
      }
      cumBefore += ps;
    }
    b1_sh = bsel;
  }
  __syncthreads();
  unsigned pre = (unsigned)b1_sh;
  size_t sbase = (size_t)s * NPS;
  const uint4* U4 = (const uint4*)(HT + sbase);
  float4* X4 = (float4*)(Xo + sbase);
  for (int i4 = chunk * 256 + tid; i4 < NPS / 4; i4 += 32 * 256) {
    uint4 v = U4[i4];
    unsigned uu[4] = {v.x, v.y, v.z, v.w};
    float oo[4];
#pragma unroll
    for (int t = 0; t < 4; ++t) {
      int il = i4 * 4 + t;
      unsigned u = uu[t] & 0x7fffffffu;
      unsigned bin = u >> 20;
      float val = __uint_as_float(uu[t]);
      if (bin > pre) {
        oo[t] = val;                 // certainly kept
        if (emit) {
          int pos = atomicAdd(&kcnt, 1);
          if (pos < 2048) { kidx[pos] = il; kval[pos] = val; }
        }
      } else if (bin < pre) {
        oo[t] = 0.0f;                // certainly zero
      } else {
        oo[t] = val;                 // uncertain: placeholder, pass3 fixes
        atomicAdd(&h[(u >> 10) & 1023], 1u);
        int pos = atomicAdd(&lcnt, 1);
        if (pos < 4096) lidx[pos] = il;
      }
    }
    X4[i4] = make_float4(oo[0], oo[1], oo[2], oo[3]);
  }
  __syncthreads();
  if (tid == 0) {
    int n = lcnt < 4096 ? lcnt : 4096;
    lbase = atomicAdd(&candcnt[s], n);
    if (emit) {
      int kn = kcnt < 2048 ? kcnt : 2048;
      kbase = atomicAdd(&nzcnt[s], kn);
    }
  }
  __syncthreads();
  int n = lcnt < 4096 ? lcnt : 4096;
  for (int e = tid; e < n; e += 256) {
    int g = lbase + e;
    if (g < CANDCAP) cand[s * CANDCAP + g] = lidx[e];
  }
  if (emit) {
    int kn = kcnt < 2048 ? kcnt : 2048;
    for (int e = tid; e < kn; e += 256) {
      int g = kbase + e;
      if (g < KSEL) { nzidx[s * KSEL + g] = kidx[e]; nzval[s * KSEL + g] = kval[e]; }
    }
  }
  for (int e = tid; e < 1024; e += 256)
    if (h[e]) atomicAdd(&g2[s * 1024 + e], h[e]);
}

// ---------------------------------------------------------------------------
// pass3_k: find1 + find2 + level-3 + tie resolution, then FIXES UP the
// uncertain elements in Xout (keep?val:0), appends kept-uncertains to the nz
// list (completing it to exactly KSEL), and zeroes this sample's g1/g2 rows
// + counters for the next iteration. One block per sample.
// ---------------------------------------------------------------------------
__global__ __launch_bounds__(256) void pass3_k(const float* __restrict__ HT,
    const int* __restrict__ cand, int* __restrict__ candcnt,
    unsigned* __restrict__ g1, unsigned* __restrict__ g2,
    float* __restrict__ Xo, int* __restrict__ nzidx, float* __restrict__ nzval,
    int* __restrict__ nzcnt, int emit) {
  int s = blockIdx.x;
  __shared__ unsigned h[1024];
  __shared__ unsigned part[256];
  __shared__ int eqidx[1024];
  __shared__ int kidx[2048];
  __shared__ float kval[2048];
  __shared__ int eqn, kcnt, kbase;
  __shared__ unsigned tau_sh;
  __shared__ int k3_sh, cutoff_sh;
  __shared__ int b1_sh, k1_sh, b2_sh, k2_sh;
  int t = threadIdx.x;
  unsigned* hg1 = g1 + (size_t)s * 2048;
  unsigned s1 = 0;
#pragma unroll
  for (int e = 0; e < 8; ++e) s1 += hg1[t * 8 + e];
  part[t] = s1;
  for (int e = t; e < 1024; e += 256) h[e] = 0;
  if (t == 0) { eqn = 0; kcnt = 0; }
  __syncthreads();
  if (t == 0) {
    int Kv = KSEL;
    unsigned cumBefore = 0;
    int bsel = 0;
    for (int q = 255; q >= 0; --q) {
      unsigned ps = part[q];
      if ((int)(cumBefore + ps) >= Kv) {
        for (int e = q * 8 + 7;; --e) {
          unsigned c2 = cumBefore + hg1[e];
          if ((int)c2 >= Kv) { bsel = e; break; }
          cumBefore = c2;
        }
        break;
      }
      cumBefore += ps;
    }
    b1_sh = bsel;
    k1_sh = Kv - (int)cumBefore;
  }
  __syncthreads();
  unsigned* hg = g2 + s * 1024;
  unsigned s2 = 0;
#pragma unroll
  for (int e = 0; e < 4; ++e) s2 += hg[t * 4 + e];
  part[t] = s2;
  __syncthreads();
  if (t == 0) {
    int Kv = k1_sh;
    unsigned cumBefore = 0;
    int bsel = 0;
    for (int q = 255; q >= 0; --q) {
      unsigned ps = part[q];
      if ((int)(cumBefore + ps) >= Kv) {
        for (int e = q * 4 + 3;; --e) {
          unsigned c2 = cumBefore + hg[e];
          if ((int)c2 >= Kv) { bsel = e; break; }
          cumBefore = c2;
        }
        break;
      }
      cumBefore += ps;
    }
    b2_sh = bsel;
    k2_sh = Kv - (int)cumBefore;
  }
  __syncthreads();
  int n = candcnt[s];
  if (n > CANDCAP) n = CANDCAP;
  unsigned pre21 = (((unsigned)b1_sh) << 10) | (unsigned)b2_sh;
  const unsigned* U = (const unsigned*)(HT + (size_t)s * NPS);
  for (int e = t; e < n; e += 256) {
    int i = cand[s * CANDCAP + e];
    unsigned u = U[i] & 0x7fffffffu;
    if ((u >> 10) == pre21) atomicAdd(&h[u & 1023], 1u);
  }
  __syncthreads();
  if (t == 0) {
    int Kv = k2_sh;
    unsigned cumBefore = 0;
    int b3 = 0;
    for (int e = 1023; e >= 0; --e) {
      unsigned c2 = cumBefore + h[e];
      if ((int)c2 >= Kv) { b3 = e; break; }
      cumBefore = c2;
    }
    tau_sh = (pre21 << 10) | (unsigned)b3;
    k3_sh = Kv - (int)cumBefore;
  }
  __syncthreads();
  unsigned tau = tau_sh;
  for (int e = t; e < n; e += 256) {
    int i = cand[s * CANDCAP + e];
    unsigned u = U[i] & 0x7fffffffu;
    if (u == tau) {
      int pos = atomicAdd(&eqn, 1);
      if (pos < 1024) eqidx[pos] = i;
    }
  }
  __syncthreads();
  if (t == 0) {
    int m = eqn < 1024 ? eqn : 1024;
    int k3 = k3_sh;
    int cutoff;
    if (k3 >= m) {
      cutoff = 0x7fffffff;
    } else {
      int last = -1;
      for (int r = 0; r < k3; ++r) {
        int mn = 0x7fffffff;
        for (int q = 0; q < m; ++q) {
          int v = eqidx[q];
          if (v > last && v < mn) mn = v;
        }
        last = mn;
      }
      cutoff = last;
    }
    cutoff_sh = cutoff;
  }
  __syncthreads();
  // ---- fixup: resolve every uncertain element in Xout; gather kept ones ----
  int co = cutoff_sh;
  float* Xs = Xo + (size_t)s * NPS;
  for (int e = t; e < n; e += 256) {
    int i = cand[s * CANDCAP + e];
    unsigned uval = U[i];
    unsigned u = uval & 0x7fffffffu;
    bool keep = (u > tau) || (u == tau && i <= co);
    float val = __uint_as_float(uval);
    Xs[i] = keep ? val : 0.0f;
    if (keep && emit) {
      int pos = atomicAdd(&kcnt, 1);
      if (pos < 2048) { kidx[pos] = i; kval[pos] = val; }
    }
  }
  __syncthreads();
  if (emit) {
    if (t == 0) {
      int kn = kcnt < 2048 ? kcnt : 2048;
      kbase = atomicAdd(&nzcnt[s], kn);
    }
    __syncthreads();
    int kn = kcnt < 2048 ? kcnt : 2048;
    for (int e = t; e < kn; e += 256) {
      int g = kbase + e;
      if (g < KSEL) { nzidx[s * KSEL + g] = kidx[e]; nzval[s * KSEL + g] = kval[e]; }
    }
  }
  __syncthreads();
  // ---- reset this sample's state for the next iteration ----
  for (int e = t; e < 2048; e += 256) hg1[e] = 0;
  for (int e = t; e < 1024; e += 256) hg[e] = 0;
  if (t == 0) { candcnt[s] = 0; nzcnt[s] = 0; }
}

extern "C" void kernel_launch(void* const* d_in, const int* in_sizes, int n_in,
                              void* d_out, int out_size, void* d_ws, size_t ws_size,
                              hipStream_t stream) {
  const float* Y  = (const float*)d_in[0];
  const float* X0 = (const float*)d_in[1];
  const float* Wg = (const float*)d_in[2];
  float* Xout = (float*)d_out;

  double* WDd  = (double*)d_ws;                        // NW f64
  double* Wt2d = WDd + NW;                             // NW f64
  float* HT   = (float*)(Wt2d + NW);                   // NTOT f32
  float* Rbuf = HT + NTOT;                             // RTOT f32
  double* Rd  = (double*)(Rbuf + RTOT);                // RTOT f64
  unsigned* g1 = (unsigned*)(Rd + RTOT);               // 32*2048
  unsigned* g2 = g1 + 32 * 2048;                       // 32*1024
  int* candcnt = (int*)(g2 + 32 * 1024);               // 32
  int* nzcnt = candcnt + 32;                           // 32
  int* cand = nzcnt + 32;                              // 32*CANDCAP
  int* nzidx = cand + 32 * CANDCAP;                    // 32*KSEL
  float* nzval = (float*)(nzidx + 32 * KSEL);          // 32*KSEL

  prep_k<<<dim3((RTOT + 255) / 256), dim3(256), 0, stream>>>(Wg, WDd, Wt2d, Y, Rd, g1);

  for (int it = 0; it < 3; ++it) {
    const float* Xsrc = (it == 0) ? X0 : (const float*)Xout;
    if (it == 0) {
      convD_k<<<dim3(2048), dim3(256), 0, stream>>>(Xsrc, WDd, Rd);
      convDt_k<double><<<dim3(4096), dim3(256), 0, stream>>>(Rd, Wt2d, Xsrc, HT, g1);
    } else {
      convD_sparse_k<<<dim3(BATCH * CCH * 8), dim3(256), 0, stream>>>(
          Wg, nzidx, nzval, Y, Rbuf);
      convDt_k<float><<<dim3(4096), dim3(256), 0, stream>>>(Rbuf, Wt2d, Xsrc, HT, g1);
    }
    int emit = (it < 2) ? 1 : 0;
    histwrite_k<<<dim3(BATCH * 32), dim3(256), 0, stream>>>(
        HT, g1, g2, cand, candcnt, Xout, nzidx, nzval, nzcnt, emit);
    pass3_k<<<dim3(BATCH), dim3(256), 0, stream>>>(
        HT, cand, candcnt, g1, g2, Xout, nzidx, nzval, nzcnt, emit);
  }
}